// Round 7
// baseline (13346.797 us; speedup 1.0000x reference)
//
#include <hip/hip_runtime.h>
#include <hip/hip_fp16.h>

typedef _Float16 f16x8 __attribute__((ext_vector_type(8)));
typedef float f32x4 __attribute__((ext_vector_type(4)));
typedef unsigned short u16;
typedef unsigned int u32;

#define T_STEPS 512
#define BATCH   512
#define DTF     0.01f

// workspace layout (bytes)
#define CTR_OFF 0
#define CTR_SZ  2228224                     // slot counters + per-(g,t,w) pipeline counters (2.1MB)
#define WB_OFF  (CTR_OFF + CTR_SZ)
#define WB_SZ   (32*2*76800)                // 4,915,200  packed W_h+W_p f16 frags, 32 slices
#define WRB_OFF (WB_OFF + WB_SZ)
#define WRB_SZ  (4*24*64*8*2)               // 98,304     W_r f16 B-frag layout
#define ST_OFF  (WRB_OFF + WRB_SZ)
#define ST_SZ   (2*512*1536*2)              // 3,145,728  state [buf][512 rows][hz 768 | hy 768] f16
#define WS_NEED (ST_OFF + ST_SZ)

#define MFMA16(a,b,c) __builtin_amdgcn_mfma_f32_16x16x32_f16((a),(b),(c),0,0,0)

// Intra-XCD acquire: L2 is the coherence point (peers on this XCD by
// construction), L1 is write-through => only L1 can be stale. L1-only inv.
// [Verified rounds 3-6.] Per-wave now (no block barrier): each wave invs
// before its own reads; read sets are disjoint per wave.
#define ACQUIRE_L1() asm volatile("s_waitcnt vmcnt(0)\n\tbuffer_inv sc0" ::: "memory")

__device__ __forceinline__ u16 f2h(float f){ _Float16 h = (_Float16)f; return *reinterpret_cast<u16*>(&h); }

__device__ __forceinline__ float ftanh(float x){
  float a = fminf(fmaxf(x, -12.f), 12.f);
  float e = __expf(2.f * a);
  return 1.f - 2.f * __builtin_amdgcn_rcpf(e + 1.f);
}

// Packed per-slice weight image (u16 units), slice s owns cols [s*24, s*24+24)
// of BOTH matrices:
//   base = s*76800 ; mat m in {0=W_h,1=W_p}: mbase = base + m*38400
//   nt0 full frags : mbase + kt*512 + l*8          (l=0..63)  col = s*24 + (l&15),   k = kt*32+(l>>4)*8
//   nt1 half frags : mbase + 25600 + kt*256 + j*8  (j=0..31)  col = s*24+16 + (j&7), k = kt*32+(j>>3)*8
// Wrb[nt(4)][kt(24)][lane(64)][8] for the final projection.
__global__ __launch_bounds__(64) void prep_weights(const float* __restrict__ Wh,
                                                   const float* __restrict__ Wp,
                                                   const float* __restrict__ Wr,
                                                   u16* __restrict__ Wb, u16* __restrict__ Wrb){
  int b = blockIdx.x, l = threadIdx.x;
  if (b < 3200){
    int s = b / 100, rem = b % 100;
    int m = rem / 50, kt = rem % 50;
    const float* W = m ? Wp : Wh;
    size_t mbase = (size_t)s*76800 + (size_t)m*38400;
    {
      int col = s*24 + (l & 15), k = kt*32 + (l >> 4)*8;
      const float* src = W + (size_t)col*1600 + k;
      f16x8 o;
#pragma unroll
      for (int e = 0; e < 8; ++e) o[e] = (_Float16)src[e];
      *reinterpret_cast<f16x8*>(Wb + mbase + (size_t)kt*512 + (size_t)l*8) = o;
    }
    if (l < 32){
      int col = s*24 + 16 + (l & 7), k = kt*32 + (l >> 3)*8;
      const float* src = W + (size_t)col*1600 + k;
      f16x8 o;
#pragma unroll
      for (int e = 0; e < 8; ++e) o[e] = (_Float16)src[e];
      *reinterpret_cast<f16x8*>(Wb + mbase + 25600 + (size_t)kt*256 + (size_t)l*8) = o;
    }
  } else {
    int b2 = b - 3200;                      // 0..95
    int nt = b2 / 24, kt = b2 % 24;
    int c = nt*16 + (l & 15), k = kt*32 + (l >> 4)*8;
    const float* src = Wr + (size_t)c*768 + k;
    f16x8 o;
#pragma unroll
    for (int e = 0; e < 8; ++e) o[e] = (_Float16)src[e];
    *reinterpret_cast<f16x8*>(Wrb + ((size_t)b2*64 + l)*8) = o;
  }
}

// grid = 256 blocks x 256 threads. Group = PHYSICAL XCD (HW_REG_XCC_ID), slot
// via atomicAdd: 32 blocks/XCD (1 block/CU by LDS). Slot s owns 24 cols of
// BOTH W_h and W_p. WAVE-GRANULAR SYNC: wave w touches only state rows
// [16w,16w+16) => 4 disjoint 32-wave pipelines per XCD, each with its own
// per-step counter. NO __syncthreads in the step loop; publish/wait per wave.
__global__ __launch_bounds__(256, 1) void rnn_main(
    const float* __restrict__ x, const float* __restrict__ bh_g, const float* __restrict__ bp_g,
    const float* __restrict__ br_g, const u16* __restrict__ Wb, const u16* __restrict__ Wrb,
    u16* __restrict__ st, u32* __restrict__ ctr, float* __restrict__ out)
{
  extern __shared__ u16 smem[];             // packed slice image, 153,600 B
  __shared__ int s_slot, s_xcd;

  const int tid = threadIdx.x;
  if (tid == 0){
    u32 xcd;
    asm volatile("s_getreg_b32 %0, hwreg(HW_REG_XCC_ID)" : "=s"(xcd));
    xcd &= 7u;
    s_xcd  = (int)xcd;
    s_slot = (int)atomicAdd(ctr + xcd, 1u); // device-scope, ctr pre-zeroed
  }
  __syncthreads();                          // (only block barrier: slot + LDS staging)
  const int g = s_xcd;
  const int s = s_slot;
  if (s >= 32) return;

  const int c0   = s * 24;
  const int l    = tid & 63;
  const int w    = tid >> 6;
  const int colL = l & 15;
  const int kq   = l >> 4;
  const int j8   = kq*8 + (l & 7);          // nt1 half-frag index (lanes colL>=8 alias colL-8)
  const int rowA = w*16 + colL;             // A-frag row (wave = m-tile pipeline)
  const int rowC = w*16 + kq*4;             // C-frag row base (add e)
  const bool v1  = (colL < 8);              // nt1 validity for this lane

  // per-(g,t,w) pipeline counters: FL + ((g*512+t)*4+w)*32, 128B stride
  u32* FL = ctr + 4096;

  // stage packed slice global -> LDS (153.6 KB)
  {
    const float4* srcw = reinterpret_cast<const float4*>(Wb + (size_t)s*76800);
    float4* dst = reinterpret_cast<float4*>(smem);
    for (int i = tid; i < 9600; i += 256) dst[i] = srcw[i];
  }
  __syncthreads();

  // biases (junk lanes read aliased-valid addresses)
  const float bh0 = bh_g[c0 + colL];
  const float bh1 = bh_g[c0 + 16 + (l & 7)];
  const float bp0 = bp_g[c0 + colL];
  const float bp1 = bp_g[c0 + 16 + (l & 7)];

  float hz0[4] = {}, hy0[4] = {}, hz1[4] = {}, hy1[4] = {};
  const f16x8* WB = reinterpret_cast<const f16x8*>(smem);
  // f16x8 index bases: WH0=0, WH1=3200, WP0=4800, WP1=8000 (u16/8)

  // per-wave wait: all lanes poll ONE dword (coalesced, uniform); monotonic
  // counter => uniform exit; s_sleep backoff; timeout bails (loud failure).
  auto wait_cnt = [&](const u32* cp)->bool{
    long spins = 0;
    while (__hip_atomic_load(cp, __ATOMIC_RELAXED, __HIP_MEMORY_SCOPE_AGENT) < 32u){
      __builtin_amdgcn_s_sleep(1);
      if (++spins > 3000000L) return false;
    }
    return true;
  };

  bool alive = true;

#pragma unroll 1
  for (int t = 0; t < T_STEPS; ++t){
    // x prefetch (independent of the tile) — issue before the wait
    const float* xb = x + ((size_t)t*BATCH + g*64 + rowA)*64 + kq*8;
    f16x8 xa[2], xs[2];
#pragma unroll
    for (int i = 0; i < 2; ++i){
      const float4 u = *reinterpret_cast<const float4*>(xb + i*32);
      const float4 v = *reinterpret_cast<const float4*>(xb + i*32 + 4);
      xa[i][0]=(_Float16)u.x; xa[i][1]=(_Float16)u.y; xa[i][2]=(_Float16)u.z; xa[i][3]=(_Float16)u.w;
      xa[i][4]=(_Float16)v.x; xa[i][5]=(_Float16)v.y; xa[i][6]=(_Float16)v.z; xa[i][7]=(_Float16)v.w;
      xs[i][0]=(_Float16)(u.x*u.x); xs[i][1]=(_Float16)(u.y*u.y); xs[i][2]=(_Float16)(u.z*u.z); xs[i][3]=(_Float16)(u.w*u.w);
      xs[i][4]=(_Float16)(v.x*v.x); xs[i][5]=(_Float16)(v.y*v.y); xs[i][6]=(_Float16)(v.z*v.z); xs[i][7]=(_Float16)(v.w*v.w);
    }

    if (t > 0 && alive)
      alive = wait_cnt(FL + ((size_t)(g*512 + (t-1))*4 + w)*32);  // pipeline-w, step t-1
    if (!alive) break;
    ACQUIRE_L1();                           // per-wave L1 inv (read set disjoint per wave)

    const u16* sbase = st + (((size_t)(t&1)*512) + g*64 + rowA)*1536 + kq*8;

    f32x4 aH0 = {}, aH1 = {}, aP0 = {}, aP1 = {};
    f16x8 ab[8];
#pragma unroll
    for (int i = 0; i < 8; ++i) ab[i] = *reinterpret_cast<const f16x8*>(sbase + (size_t)i*32);

#pragma unroll
    for (int i = 0; i < 50; ++i){
      f16x8 a, asq;
      int kt;
      if (i < 48){
        a = ab[i & 7];
        if (i + 8 < 48) ab[i & 7] = *reinterpret_cast<const f16x8*>(sbase + (size_t)(i+8)*32);
        asq = a*a;
        kt = i + 2;
      } else {
        a = xa[i-48]; asq = xs[i-48]; kt = i - 48;
      }
      aH0 = MFMA16(a,   WB[       kt*64 + l ], aH0);
      aH1 = MFMA16(a,   WB[3200 + kt*32 + j8], aH1);
      aP0 = MFMA16(asq, WB[4800 + kt*64 + l ], aP0);
      aP1 = MFMA16(asq, WB[8000 + kt*32 + j8], aP1);
    }

    // local update: hp never leaves the block (consumed in fp32)
    u16* wt = st + ((size_t)((t+1)&1)*512 + g*64)*1536;
#pragma unroll
    for (int e = 0; e < 4; ++e){
      const size_t rb = (size_t)(rowC + e)*1536;
      {
        float hv = ftanh(aH0[e] + bh0), pv = ftanh(aP0[e] + bp0);
        hz0[e] += DTF * (hv + pv);
        hy0[e] += DTF * hz0[e];
        wt[rb + c0 + colL]       = f2h(hz0[e]);
        wt[rb + 768 + c0 + colL] = f2h(hy0[e]);
      }
      {
        float hv = ftanh(aH1[e] + bh1), pv = ftanh(aP1[e] + bp1);
        hz1[e] += DTF * (hv + pv);
        hy1[e] += DTF * hz1[e];
        if (v1){
          wt[rb + c0 + 16 + colL]       = f2h(hz1[e]);
          wt[rb + 768 + c0 + 16 + colL] = f2h(hy1[e]);
        }
      }
    }
    asm volatile("s_waitcnt vmcnt(0)" ::: "memory");     // this wave's stores in XCD L2
    if (l == 0)
      __hip_atomic_fetch_add(FL + ((size_t)(g*512 + t)*4 + w)*32, 1u,
                             __ATOMIC_RELAXED, __HIP_MEMORY_SCOPE_AGENT);
  }

  // final projection: out = hy @ W_r^T + b_r, by slot-0 block, per-wave
  // (wave w reads only rows [16w,16w+16) of hy — pipeline-w data).
  if (s == 0 && alive){
    if (wait_cnt(FL + ((size_t)(g*512 + (T_STEPS-1))*4 + w)*32)){
      ACQUIRE_L1();
      // tile 512 in buf0; hy section at col offset 768
      const u16* hyb = st + ((size_t)g*64 + rowA)*1536 + 768 + kq*8;
      const f16x8* Wr8 = reinterpret_cast<const f16x8*>(Wrb);
      f32x4 oc[4] = {};
#pragma unroll
      for (int kt = 0; kt < 24; ++kt){
        f16x8 a = *reinterpret_cast<const f16x8*>(hyb + (size_t)kt*32);
#pragma unroll
        for (int nt = 0; nt < 4; ++nt)
          oc[nt] = MFMA16(a, Wr8[(nt*24 + kt)*64 + l], oc[nt]);
      }
#pragma unroll
      for (int nt = 0; nt < 4; ++nt){
        float bb = br_g[nt*16 + colL];
#pragma unroll
        for (int e = 0; e < 4; ++e)
          out[(size_t)(g*64 + rowC + e)*64 + nt*16 + colL] = oc[nt][e] + bb;
      }
    }
  }
}

extern "C" void kernel_launch(void* const* d_in, const int* in_sizes, int n_in,
                              void* d_out, int out_size, void* d_ws, size_t ws_size,
                              hipStream_t stream) {
  const float* x  = (const float*)d_in[0];
  const float* Wh = (const float*)d_in[1];
  const float* bh = (const float*)d_in[2];
  const float* Wp = (const float*)d_in[3];
  const float* bp = (const float*)d_in[4];
  const float* Wr = (const float*)d_in[5];
  const float* br = (const float*)d_in[6];
  float* out = (float*)d_out;

  if (ws_size < (size_t)WS_NEED) return;    // loud failure: output stays zero
  char* ws = (char*)d_ws;

  u16* Wb  = (u16*)(ws + WB_OFF);
  u16* Wrb = (u16*)(ws + WRB_OFF);
  u16* st  = (u16*)(ws + ST_OFF);
  u32* ctr = (u32*)(ws + CTR_OFF);

  hipMemsetAsync(ws + CTR_OFF, 0, CTR_SZ, stream);   // slot + pipeline counters
  hipMemsetAsync(ws + ST_OFF,  0, ST_SZ,  stream);   // zero initial state tiles

  prep_weights<<<3296, 64, 0, stream>>>(Wh, Wp, Wr, Wb, Wrb);

  (void)hipFuncSetAttribute(reinterpret_cast<const void*>(rnn_main),
                            hipFuncAttributeMaxDynamicSharedMemorySize, 153600);
  rnn_main<<<256, 256, 153600, stream>>>(x, bh, bp, br, Wb, Wrb, st, ctr, out);
}

// Round 8
// 11904.575 us; speedup vs baseline: 1.1211x; 1.1211x over previous
//
#include <hip/hip_runtime.h>
#include <hip/hip_fp16.h>

typedef _Float16 f16x8 __attribute__((ext_vector_type(8)));
typedef float f32x4 __attribute__((ext_vector_type(4)));
typedef unsigned short u16;
typedef unsigned int u32;
typedef unsigned long long u64;

#define T_STEPS 512
#define BATCH   512
#define DTF     0.01f

// workspace layout (bytes)
#define CTR_OFF 0
#define CTR_SZ  262144                      // slot counters + per-(g,slot) monotonic flags
#define WB_OFF  (CTR_OFF + CTR_SZ)
#define WB_SZ   (32*2*76800)                // 4,915,200  packed W_h+W_p f16 frags (K-permuted)
#define WRB_OFF (WB_OFF + WB_SZ)
#define WRB_SZ  (4*24*64*8*2)               // 98,304     W_r f16 B-frag layout
#define ST_OFF  (WRB_OFF + WRB_SZ)
#define ST_SZ   (2*512*1536*2)              // 3,145,728  state [buf][512 rows][1536 cols, slot-grouped]
#define WS_NEED (ST_OFF + ST_SZ)

#define MFMA16(a,b,c) __builtin_amdgcn_mfma_f32_16x16x32_f16((a),(b),(c),0,0,0)

// Intra-XCD acquire: L2 is the coherence point (peers on this XCD by
// construction), L1 is write-through => only L1 can be stale. L1-only inv.
// [Verified rounds 3-7.]
#define ACQUIRE_L1() asm volatile("s_waitcnt vmcnt(0)\n\tbuffer_inv sc0" ::: "memory")

__device__ __forceinline__ u16 f2h(float f){ _Float16 h = (_Float16)f; return *reinterpret_cast<u16*>(&h); }

__device__ __forceinline__ float ftanh(float x){
  float a = fminf(fmaxf(x, -12.f), 12.f);
  float e = __expf(2.f * a);
  return 1.f - 2.f * __builtin_amdgcn_rcpf(e + 1.f);
}

// K-permutation: global K order = [x: 0..63][slot0: hz24,hy24][slot1: ...]...
// q>=64: c=q-64, s2=c/48, o2=c%48; src = o2<24 ? 64+s2*24+o2 : 832+s2*24+(o2-24)
__device__ __forceinline__ int perm_k(int q){
  if (q < 64) return q;
  int c = q - 64, s2 = c / 48, o2 = c % 48;
  return (o2 < 24) ? (64 + s2*24 + o2) : (832 + s2*24 + (o2 - 24));
}

// Packed per-slice weight image (u16 units), slice s owns out-cols [s*24,+24)
// of BOTH matrices; K-dim PERMUTED per perm_k:
//   base = s*76800 ; mat m in {0=W_h,1=W_p}: mbase = base + m*38400
//   nt0 full frags : mbase + kt*512 + l*8          (l=0..63)
//   nt1 half frags : mbase + 25600 + kt*256 + j*8  (j=0..31)
// Wrb[nt(4)][kt(24)][lane(64)][8] for the final projection (source hy order).
__global__ __launch_bounds__(64) void prep_weights(const float* __restrict__ Wh,
                                                   const float* __restrict__ Wp,
                                                   const float* __restrict__ Wr,
                                                   u16* __restrict__ Wb, u16* __restrict__ Wrb){
  int b = blockIdx.x, l = threadIdx.x;
  if (b < 3200){
    int s = b / 100, rem = b % 100;
    int m = rem / 50, kt = rem % 50;
    const float* W = m ? Wp : Wh;
    size_t mbase = (size_t)s*76800 + (size_t)m*38400;
    {
      int col = s*24 + (l & 15), kpos = kt*32 + (l >> 4)*8;
      f16x8 o;
#pragma unroll
      for (int e = 0; e < 8; ++e) o[e] = (_Float16)W[(size_t)col*1600 + perm_k(kpos + e)];
      *reinterpret_cast<f16x8*>(Wb + mbase + (size_t)kt*512 + (size_t)l*8) = o;
    }
    if (l < 32){
      int col = s*24 + 16 + (l & 7), kpos = kt*32 + (l >> 3)*8;
      f16x8 o;
#pragma unroll
      for (int e = 0; e < 8; ++e) o[e] = (_Float16)W[(size_t)col*1600 + perm_k(kpos + e)];
      *reinterpret_cast<f16x8*>(Wb + mbase + 25600 + (size_t)kt*256 + (size_t)l*8) = o;
    }
  } else {
    int b2 = b - 3200;                      // 0..95
    int nt = b2 / 24, kt = b2 % 24;
    int c = nt*16 + (l & 15), k = kt*32 + (l >> 4)*8;
    const float* src = Wr + (size_t)c*768 + k;
    f16x8 o;
#pragma unroll
    for (int e = 0; e < 8; ++e) o[e] = (_Float16)src[e];
    *reinterpret_cast<f16x8*>(Wrb + ((size_t)b2*64 + l)*8) = o;
  }
}

// grid = 256 x 256. Group = PHYSICAL XCD (HW_REG_XCC_ID), slot via atomicAdd.
// Slot s owns out-cols [s*24,+24) of BOTH W_h/W_p; stores its hz/hy into tile
// cols [s*48,+48) (slot-grouped). CONSUMPTION IS COMPLETION-ORDERED: granule
// g (slots 4g..4g+3, tile cols [g*192,+192) = 384B = 3 cache lines, 6 K-tiles)
// is MFMA'd as soon as its 4 producers have published — the GEMM overlaps the
// straggler window; serial chain/step = observe + 1 granule + update/publish.
__global__ __launch_bounds__(256, 1) void rnn_main(
    const float* __restrict__ x, const float* __restrict__ bh_g, const float* __restrict__ bp_g,
    const float* __restrict__ br_g, const u16* __restrict__ Wb, const u16* __restrict__ Wrb,
    u16* __restrict__ st, u32* __restrict__ ctr, float* __restrict__ out)
{
  extern __shared__ u16 smem[];             // packed slice image, 153,600 B
  __shared__ int s_slot, s_xcd;

  const int tid = threadIdx.x;
  if (tid == 0){
    u32 xcd;
    asm volatile("s_getreg_b32 %0, hwreg(HW_REG_XCC_ID)" : "=s"(xcd));
    xcd &= 7u;
    s_xcd  = (int)xcd;
    s_slot = (int)atomicAdd(ctr + xcd, 1u); // device-scope, ctr pre-zeroed
  }
  __syncthreads();
  const int g = s_xcd;
  const int s = s_slot;
  if (s >= 32) return;

  const int l    = tid & 63;
  const int w    = tid >> 6;
  const int colL = l & 15;
  const int kq   = l >> 4;
  const int j8   = kq*8 + (l & 7);          // nt1 half-frag index (lanes colL>=8 alias colL-8)
  const int rowA = w*16 + colL;             // A-frag row (wave = m-tile)
  const int rowC = w*16 + kq*4;             // C-frag row base (add e)
  const bool v1  = (colL < 8);              // nt1 validity

  // monotonic per-(g,slot) flags: FL[s*32], 128B stride. flag==t+1 <=> slot
  // finished step t (tile t+1 written & drained; reads of tile t done).
  u32* FL = ctr + 2048 + (size_t)g*1024;

  // stage packed slice global -> LDS (153.6 KB)
  {
    const float4* srcw = reinterpret_cast<const float4*>(Wb + (size_t)s*76800);
    float4* dst = reinterpret_cast<float4*>(smem);
    for (int i = tid; i < 9600; i += 256) dst[i] = srcw[i];
  }
  __syncthreads();

  const float bh0 = bh_g[s*24 + colL];
  const float bh1 = bh_g[s*24 + 16 + (l & 7)];
  const float bp0 = bp_g[s*24 + colL];
  const float bp1 = bp_g[s*24 + 16 + (l & 7)];

  float hz0[4] = {}, hy0[4] = {}, hz1[4] = {}, hy1[4] = {};
  const f16x8* WB = reinterpret_cast<const f16x8*>(smem);
  // f16x8 bases: WH0=0, WH1=3200, WP0=4800, WP1=8000

  bool alive = true;

#pragma unroll 1
  for (int t = 0; t < T_STEPS; ++t){
    // x prefetch + convert (independent of the tile)
    const float* xb = x + ((size_t)t*BATCH + g*64 + rowA)*64 + kq*8;
    f16x8 xa[2], xs[2];
#pragma unroll
    for (int i = 0; i < 2; ++i){
      const float4 u = *reinterpret_cast<const float4*>(xb + i*32);
      const float4 v = *reinterpret_cast<const float4*>(xb + i*32 + 4);
      xa[i][0]=(_Float16)u.x; xa[i][1]=(_Float16)u.y; xa[i][2]=(_Float16)u.z; xa[i][3]=(_Float16)u.w;
      xa[i][4]=(_Float16)v.x; xa[i][5]=(_Float16)v.y; xa[i][6]=(_Float16)v.z; xa[i][7]=(_Float16)v.w;
      xs[i][0]=(_Float16)(u.x*u.x); xs[i][1]=(_Float16)(u.y*u.y); xs[i][2]=(_Float16)(u.z*u.z); xs[i][3]=(_Float16)(u.w*u.w);
      xs[i][4]=(_Float16)(v.x*v.x); xs[i][5]=(_Float16)(v.y*v.y); xs[i][6]=(_Float16)(v.z*v.z); xs[i][7]=(_Float16)(v.w*v.w);
    }

    ACQUIRE_L1();                           // before any tile-t reads

    f32x4 aH0 = {}, aH1 = {}, aP0 = {}, aP1 = {};
    // x chunk first (no dependency) — work during the straggler window
#pragma unroll
    for (int i = 0; i < 2; ++i){
      aH0 = MFMA16(xa[i], WB[       i*64 + l ], aH0);
      aH1 = MFMA16(xa[i], WB[3200 + i*32 + j8], aH1);
      aP0 = MFMA16(xs[i], WB[4800 + i*64 + l ], aP0);
      aP1 = MFMA16(xs[i], WB[8000 + i*32 + j8], aP1);
    }

    // completion-order granule loop
    const u16* sb = st + (((size_t)(t&1)*512) + g*64 + rowA)*1536 + kq*8;
    u32 pendingG = 0xFFu;
    long spins = 0;
    while (pendingG){
      u32 fv = 0;
      if (l < 32) fv = __hip_atomic_load(FL + l*32, __ATOMIC_RELAXED, __HIP_MEMORY_SCOPE_AGENT);
      u64 bal = __ballot((l < 32) && (fv >= (u32)t));
      u32 rm = (u32)bal;
      u32 q4 = rm & (rm >> 1) & (rm >> 2) & (rm >> 3);
      u32 ready = 0;
#pragma unroll
      for (int gg = 0; gg < 8; ++gg) ready |= ((q4 >> (4*gg)) & 1u) << gg;
      u32 newm = ready & pendingG;
      if (newm){
        asm volatile("" ::: "memory");      // no load hoisting above flag observation
        do {
          int gg = __builtin_ctz(newm); newm &= newm - 1;
          const u16* gb = sb + gg*192;
          f16x8 av[6];
#pragma unroll
          for (int j = 0; j < 6; ++j) av[j] = *reinterpret_cast<const f16x8*>(gb + (size_t)j*32);
#pragma unroll
          for (int j = 0; j < 6; ++j){
            f16x8 a = av[j], asq = a*a;
            const int kt = 6*gg + j + 2;
            aH0 = MFMA16(a,   WB[       kt*64 + l ], aH0);
            aH1 = MFMA16(a,   WB[3200 + kt*32 + j8], aH1);
            aP0 = MFMA16(asq, WB[4800 + kt*64 + l ], aP0);
            aP1 = MFMA16(asq, WB[8000 + kt*32 + j8], aP1);
          }
        } while (newm);
        pendingG &= ~ready;
      } else {
        if (++spins > 2000000L){ alive = false; break; }
      }
    }
    if (!alive) break;

    // local update; store into slot-grouped cols [s*48, s*48+48)
    u16* wt = st + ((size_t)((t+1)&1)*512 + g*64)*1536;
#pragma unroll
    for (int e = 0; e < 4; ++e){
      const size_t rb = (size_t)(rowC + e)*1536;
      {
        float hv = ftanh(aH0[e] + bh0), pv = ftanh(aP0[e] + bp0);
        hz0[e] += DTF * (hv + pv);
        hy0[e] += DTF * hz0[e];
        wt[rb + s*48 + colL]      = f2h(hz0[e]);
        wt[rb + s*48 + 24 + colL] = f2h(hy0[e]);
      }
      {
        float hv = ftanh(aH1[e] + bh1), pv = ftanh(aP1[e] + bp1);
        hz1[e] += DTF * (hv + pv);
        hy1[e] += DTF * hz1[e];
        if (v1){
          wt[rb + s*48 + 16 + (l & 7)] = f2h(hz1[e]);
          wt[rb + s*48 + 40 + (l & 7)] = f2h(hy1[e]);
        }
      }
    }
    asm volatile("s_waitcnt vmcnt(0)" ::: "memory");     // block's stores in XCD L2
    __syncthreads();
    if (tid == 0)
      __hip_atomic_store(FL + s*32, (u32)(t+1), __ATOMIC_RELAXED, __HIP_MEMORY_SCOPE_AGENT);
  }

  // final projection by slot-0 block (per wave; rows [16w,+16))
  if (s == 0 && alive){
    long spins = 0; bool ok = true;
    for (;;){
      u32 fv = 0xFFFFFFFFu;
      if (l < 32) fv = __hip_atomic_load(FL + l*32, __ATOMIC_RELAXED, __HIP_MEMORY_SCOPE_AGENT);
      if (__all(fv >= (u32)T_STEPS)) break;
      __builtin_amdgcn_s_sleep(1);
      if (++spins > 4000000L){ ok = false; break; }
    }
    if (ok){
      ACQUIRE_L1();
      // tile 512 in buf0; hy dim d lives at col (d/24)*48 + 24 + d%24
      const u16* hyrow = st + ((size_t)g*64 + rowA)*1536;
      const f16x8* Wr8 = reinterpret_cast<const f16x8*>(Wrb);
      f32x4 oc[4] = {};
#pragma unroll
      for (int kt = 0; kt < 24; ++kt){
        int d = kt*32 + kq*8;
        int col = (d/24)*48 + 24 + (d % 24);
        f16x8 a = *reinterpret_cast<const f16x8*>(hyrow + col);
#pragma unroll
        for (int nt = 0; nt < 4; ++nt)
          oc[nt] = MFMA16(a, Wr8[(nt*24 + kt)*64 + l], oc[nt]);
      }
#pragma unroll
      for (int nt = 0; nt < 4; ++nt){
        float bb = br_g[nt*16 + colL];
#pragma unroll
        for (int e = 0; e < 4; ++e)
          out[(size_t)(g*64 + rowC + e)*64 + nt*16 + colL] = oc[nt][e] + bb;
      }
    }
  }
}

extern "C" void kernel_launch(void* const* d_in, const int* in_sizes, int n_in,
                              void* d_out, int out_size, void* d_ws, size_t ws_size,
                              hipStream_t stream) {
  const float* x  = (const float*)d_in[0];
  const float* Wh = (const float*)d_in[1];
  const float* bh = (const float*)d_in[2];
  const float* Wp = (const float*)d_in[3];
  const float* bp = (const float*)d_in[4];
  const float* Wr = (const float*)d_in[5];
  const float* br = (const float*)d_in[6];
  float* out = (float*)d_out;

  if (ws_size < (size_t)WS_NEED) return;    // loud failure: output stays zero
  char* ws = (char*)d_ws;

  u16* Wb  = (u16*)(ws + WB_OFF);
  u16* Wrb = (u16*)(ws + WRB_OFF);
  u16* st  = (u16*)(ws + ST_OFF);
  u32* ctr = (u32*)(ws + CTR_OFF);

  hipMemsetAsync(ws + CTR_OFF, 0, CTR_SZ, stream);   // slot counters + flags
  hipMemsetAsync(ws + ST_OFF,  0, ST_SZ,  stream);   // zero initial state tiles

  prep_weights<<<3296, 64, 0, stream>>>(Wh, Wp, Wr, Wb, Wrb);

  (void)hipFuncSetAttribute(reinterpret_cast<const void*>(rnn_main),
                            hipFuncAttributeMaxDynamicSharedMemorySize, 153600);
  rnn_main<<<256, 256, 153600, stream>>>(x, bh, bp, br, Wb, Wrb, st, ctr, out);
}